// Round 7
// baseline (321.635 us; speedup 1.0000x reference)
//
#include <hip/hip_runtime.h>
#include <hip/hip_bf16.h>
#include <stdint.h>

typedef __bf16 bf16_t;
typedef bf16_t bf16x8 __attribute__((ext_vector_type(8)));
typedef float f32x4 __attribute__((ext_vector_type(4)));

#define T_LEN 2048
#define C_LEN 2048
#define NB 128
#define TN 256
#define SROWS 2064    // 16 zero-halo rows + 2048 data rows per batch
#define XROWS 288     // 18 x 2KB GLL rounds (128 thr); rows 0..271 consumed

// async global->LDS, 16B per lane; LDS dest = wave-uniform base + lane*16
#define GLL(gp, lp) __builtin_amdgcn_global_load_lds( \
    (const __attribute__((address_space(1))) uint32_t*)(gp), \
    (__attribute__((address_space(3))) uint32_t*)(lp), 16, 0, 0)

// ---------------------------------------------------------------------------
// Prepack weights into per-lane MFMA A-fragment layout (verified r1-r6):
// wpk[blk][ks(32)][mt(4)][lane(64)][j(8)]
//   = bv[blk][o = mt*16 + (lane&15)][i = (ks&1)*32 + (lane>>4)*8 + j][k = ks>>1]
// ---------------------------------------------------------------------------
__global__ __launch_bounds__(256) void prepack_kernel(
    const float* __restrict__ bv, bf16_t* __restrict__ wpk)
{
  const int blk = blockIdx.x;
  const int mt  = blockIdx.y;
  const int tid = threadIdx.x;
  __shared__ float lw[16 * 64 * 17];

  const float* src = bv + (size_t)blk * 65536 + (size_t)mt * 16384;
  for (int p = 0; p < 16; ++p) {
    int idx = p * 1024 + tid * 4;
    const float4 v = *(const float4*)(src + idx);
    int o = idx >> 10;
    int i = (idx >> 4) & 63;
    int k = idx & 15;
    float* d = &lw[(o * 64 + i) * 17 + k];
    d[0] = v.x; d[1] = v.y; d[2] = v.z; d[3] = v.w;
  }
  __syncthreads();

  const int e0 = tid * 2;
  const int l  = e0 >> 3;
  const int j  = e0 & 7;
  const int o  = l & 15;
  for (int ks = 0; ks < 32; ++ks) {
    const int k  = ks >> 1;
    const int i0 = (ks & 1) * 32 + (l >> 4) * 8 + j;
    const float a = lw[(o * 64 + i0) * 17 + k];
    const float b = lw[(o * 64 + i0 + 1) * 17 + k];
    const uint16_t ba = __builtin_bit_cast(uint16_t, (bf16_t)a);
    const uint16_t bb = __builtin_bit_cast(uint16_t, (bf16_t)b);
    const uint32_t packed = (uint32_t)ba | ((uint32_t)bb << 16);
    const size_t off = ((((size_t)blk * 32 + ks) * 4 + mt) * 512) + e0;
    *(uint32_t*)(wpk + off) = packed;
  }
}

// ---------------------------------------------------------------------------
// Zero the halo rows of S.
// ---------------------------------------------------------------------------
__global__ __launch_bounds__(256) void padzero_kernel(bf16_t* __restrict__ S)
{
  const int p = blockIdx.x;  // 0..79
  const size_t g = (p < 64) ? ((size_t)(p >> 4) * SROWS + (p & 15))
                            : ((size_t)4 * SROWS + (p - 64));
  uint4 z = {0u, 0u, 0u, 0u};
  *(uint4*)(S + g * C_LEN + (size_t)threadIdx.x * 8) = z;
}

// ---------------------------------------------------------------------------
// x prepass: f32 [n][c][t] -> bf16 S[n][16+t][c'], c' = c ^ ((t&7)<<3)
// within each 64-ch block (XOR swizzle baked into global layout).
// ---------------------------------------------------------------------------
__global__ __launch_bounds__(256) void xprep_kernel(
    const float* __restrict__ x, bf16_t* __restrict__ S)
{
  const int tb = blockIdx.x, cb = blockIdx.y, n = blockIdx.z;
  const int tid = threadIdx.x;
  __shared__ float lt[64 * 67 + 4];

  #pragma unroll
  for (int p = 0; p < 4; ++p) {
    const int idx = p * 256 + tid;
    const int c   = idx >> 4;
    const int t4  = (idx & 15) * 4;
    const float4 v = *(const float4*)(
        x + ((size_t)n * C_LEN + cb * 64 + c) * T_LEN + tb * 64 + t4);
    float* d = &lt[c * 67 + t4];
    d[0] = v.x; d[1] = v.y; d[2] = v.z; d[3] = v.w;
  }
  __syncthreads();

  #pragma unroll
  for (int p = 0; p < 2; ++p) {
    const int idx = p * 256 + tid;
    const int tl  = idx >> 3;
    const int seg = idx & 7;
    const int t   = tb * 64 + tl;
    const int cbase = (seg * 8) ^ ((t & 7) << 3);
    uint32_t w[4];
    #pragma unroll
    for (int h = 0; h < 4; ++h) {
      const float a = lt[(cbase + 2 * h) * 67 + tl];
      const float b = lt[(cbase + 2 * h + 1) * 67 + tl];
      const uint16_t ba = __builtin_bit_cast(uint16_t, (bf16_t)a);
      const uint16_t bb = __builtin_bit_cast(uint16_t, (bf16_t)b);
      w[h] = (uint32_t)ba | ((uint32_t)bb << 16);
    }
    uint4 u4 = {w[0], w[1], w[2], w[3]};
    *(uint4*)(S + ((size_t)n * SROWS + 16 + t) * C_LEN + cb * 64 + seg * 8) = u4;
  }
}

// ---------------------------------------------------------------------------
// Main kernel: 128 thr (2 waves), ~53 KB LDS -> 3 WG/CU (6 waves/CU).
// Wave wv: output rows [tr*64,+64) x t-cols [t0+wv*128,+128)  (mt=4, nt=8:
// 384 B LDS per MFMA vs r6's 512; 32-MFMA stretch per 12 reads gives the
// within-wave ILP needed to overlap the LDS pipe with the matrix pipe).
// - x: single buffer, 18 x 2KB GLL at block top (after prev trailing
//   barrier -- all xst reads complete, r6-proven safe vs DMA write).
// - W: 2 x 8KB chunk double-buffer (2 ks/chunk, 16 chunks/block), GLL.
// Counted vmcnt ledger (GLL-only, uniform, FIFO-verified):
//  entry to block j c=0: [x(j):18, W(j,0):4] outstanding.
//  c<15: issue W(j,c+1):4, wait vmcnt(4)  (everything older has landed)
//  c=15: issue W(j+1,0):4, wait vmcnt(4)  (last block: wait vmcnt(0))
// ---------------------------------------------------------------------------
__global__ __launch_bounds__(128, 2) void bsconv_kernel(
    const bf16_t* __restrict__ S, const bf16_t* __restrict__ wpk,
    const int* __restrict__ cols, const int* __restrict__ rows,
    float* __restrict__ y)
{
  const int tt = blockIdx.x, tr = blockIdx.y, n = blockIdx.z;
  const int t0 = tt * TN;
  const int tid = threadIdx.x;
  const int lane = tid & 63, wv = tid >> 6;   // wv 0..1

  __shared__ __attribute__((aligned(16))) bf16_t xst[XROWS * 64];  // 36864 B
  __shared__ __attribute__((aligned(16))) bf16_t wlds[2][4096];    // 16384 B
  __shared__ int alist[NB];                   // packed: blk | (col<<8)
  __shared__ unsigned long long wmask[2];

  // ---- build active-block list (order-preserving => deterministic) ----
  {
    const int r = rows[tid];                  // tid 0..127 == blk id
    const int cb = cols[tid];
    const bool match = (r == tr);
    const unsigned long long m = __ballot(match);
    if (lane == 0) wmask[wv] = m;
    __syncthreads();
    if (match) {
      int pos = __popcll(wmask[wv] & ((1ull << lane) - 1ull));
      if (wv == 1) pos += __popcll(wmask[0]);
      alist[pos] = tid | (cb << 8);
    }
    __syncthreads();   // also drains all vmem: ledger starts at 0
  }
  const int cnt = __popcll(wmask[0]) + __popcll(wmask[1]);

  f32x4 acc[4][8];
  #pragma unroll
  for (int a = 0; a < 4; ++a)
    #pragma unroll
    for (int b = 0; b < 8; ++b) {
      f32x4 z = {0.f, 0.f, 0.f, 0.f};
      acc[a][b] = z;
    }

  const size_t srow0 = (size_t)n * SROWS + t0;  // S row of LDS row u=0
  const int lxb = tid * 16;                     // lane byte within a 2KB round

  auto issue_x = [&](int cb) {                  // 18 rounds = 36 KB, single buf
    #pragma unroll
    for (int q = 0; q < 18; ++q) {
      const int lb = q * 2048 + lxb;
      const int u  = lb >> 7;                   // LDS row (128 B rows)
      const int ib = (lb >> 1) & 63;
      GLL(S + (srow0 + u) * C_LEN + cb * 64 + ib, (char*)xst + lb);
    }
  };
  auto issue_w = [&](const bf16_t* wsrc, int buf) {  // 4 rounds = 8 KB
    #pragma unroll
    for (int p = 0; p < 4; ++p) {
      const int lb = p * 2048 + lxb;
      GLL(wsrc + (lb >> 1), (char*)wlds[buf] + lb);
    }
  };

  if (cnt > 0) {
    issue_x(alist[0] >> 8);                           // x(0):18
    issue_w(wpk + (size_t)(alist[0] & 255) * 65536, 0);  // W(0,0):4
  }

  for (int j = 0; j < cnt; ++j) {
    const bf16_t* wblk = wpk + (size_t)(alist[j] & 255) * 65536;
    const bool havenext = (j + 1 < cnt);
    const int anext = havenext ? alist[j + 1] : 0;

    #pragma unroll
    for (int c = 0; c < 16; ++c) {
      // ---- issues (program order = FIFO ledger) ----
      if (c < 15) {
        issue_w(wblk + (size_t)(c + 1) * 4096, (c + 1) & 1);
      } else if (havenext) {
        issue_w(wpk + (size_t)(anext & 255) * 65536, 0);  // next block chunk0
      }

      // ---- counted wait ----
      if (c < 15 || havenext) {
        asm volatile("s_waitcnt vmcnt(4)" ::: "memory");
      } else {
        asm volatile("s_waitcnt vmcnt(0)" ::: "memory");
      }
      __builtin_amdgcn_s_barrier();       // B_ready(c)
      __builtin_amdgcn_sched_barrier(0);

      const bf16_t* wl = wlds[c & 1];
      __builtin_amdgcn_s_setprio(1);
      #pragma unroll
      for (int ksl = 0; ksl < 2; ++ksl) {
        const int k  = c;                     // conv tap (= ks>>1)
        const int ih = ksl * 32;              // channel half
        bf16x8 afr[4];
        #pragma unroll
        for (int mt = 0; mt < 4; ++mt)
          afr[mt] = *(const bf16x8*)(wl + ((ksl * 4 + mt) * 64 + lane) * 8);
        const int ub   = wv * 128 + (lane & 15) + k + 1;
        const int scol = (ih + ((lane >> 4) & 3) * 8) ^ ((ub & 7) << 3);
        bf16x8 bfr[8];
        #pragma unroll
        for (int nt = 0; nt < 8; ++nt)
          bfr[nt] = *(const bf16x8*)(xst + (ub + nt * 16) * 64 + scol);
        #pragma unroll
        for (int mt = 0; mt < 4; ++mt)
          #pragma unroll
          for (int nt = 0; nt < 8; ++nt)
            acc[mt][nt] = __builtin_amdgcn_mfma_f32_16x16x32_bf16(
                afr[mt], bfr[nt], acc[mt][nt], 0, 0, 0);
      }
      __builtin_amdgcn_s_setprio(0);
      __builtin_amdgcn_sched_barrier(0);
      __builtin_amdgcn_s_barrier();       // B_done(c): buffers reusable
    }

    // next block's x into the single buffer: all waves are past c=15's
    // trailing barrier (xst reads complete), so the DMA overwrite is safe.
    if (havenext) issue_x(anext >> 8);
  }

  // ---- store (each output element exactly once; empty rows store zeros) ----
  const int mlo = ((lane >> 4) & 3) * 4, nn = lane & 15;
  #pragma unroll
  for (int mt = 0; mt < 4; ++mt) {
    #pragma unroll
    for (int nt = 0; nt < 8; ++nt) {
      const int t = t0 + wv * 128 + nt * 16 + nn;
      float* yp = y + ((size_t)n * C_LEN + (size_t)(tr * 64 + mt * 16 + mlo)) * T_LEN + t;
      #pragma unroll
      for (int r = 0; r < 4; ++r)
        yp[(size_t)r * T_LEN] = acc[mt][nt][r];
    }
  }
}

extern "C" void kernel_launch(void* const* d_in, const int* in_sizes, int n_in,
                              void* d_out, int out_size, void* d_ws, size_t ws_size,
                              hipStream_t stream) {
  const float* x   = (const float*)d_in[0];
  const float* bv  = (const float*)d_in[1];
  const int* cols  = (const int*)d_in[2];
  const int* rows  = (const int*)d_in[3];
  float* y = (float*)d_out;

  // ws layout: [wpk: 16,777,216 B][S: 33,882,112 B]  (needs ws >= 50.7 MB)
  bf16_t* wpk = (bf16_t*)d_ws;
  bf16_t* S   = (bf16_t*)((char*)d_ws + 16777216);

  prepack_kernel<<<dim3(128, 4), dim3(256), 0, stream>>>(bv, wpk);
  padzero_kernel<<<dim3(80), dim3(256), 0, stream>>>(S);
  xprep_kernel<<<dim3(32, 32, 4), dim3(256), 0, stream>>>(x, S);
  bsconv_kernel<<<dim3(8, 32, 4), dim3(128), 0, stream>>>(S, wpk, cols, rows, y);
}

// Round 8
// 175.640 us; speedup vs baseline: 1.8312x; 1.8312x over previous
//
#include <hip/hip_runtime.h>
#include <hip/hip_bf16.h>
#include <stdint.h>

typedef __bf16 bf16_t;
typedef bf16_t bf16x8 __attribute__((ext_vector_type(8)));
typedef float f32x4 __attribute__((ext_vector_type(4)));

#define T_LEN 2048
#define C_LEN 2048
#define NB 128
#define TN 256
#define SROWS 2064    // 16 zero-halo rows + 2048 data rows per batch
#define XROWS 288     // 9 x 4KB GLL rounds (256 thr); rows 0..271 consumed

// async global->LDS, 16B per lane; LDS dest = wave-uniform base + lane*16
#define GLL(gp, lp) __builtin_amdgcn_global_load_lds( \
    (const __attribute__((address_space(1))) uint32_t*)(gp), \
    (__attribute__((address_space(3))) uint32_t*)(lp), 16, 0, 0)

// ---------------------------------------------------------------------------
// Prepack weights into per-lane MFMA A-fragment layout (verified r1-r7):
// wpk[blk][ks(32)][mt(4)][lane(64)][j(8)]
//   = bv[blk][o = mt*16 + (lane&15)][i = (ks&1)*32 + (lane>>4)*8 + j][k = ks>>1]
// ---------------------------------------------------------------------------
__global__ __launch_bounds__(256) void prepack_kernel(
    const float* __restrict__ bv, bf16_t* __restrict__ wpk)
{
  const int blk = blockIdx.x;
  const int mt  = blockIdx.y;
  const int tid = threadIdx.x;
  __shared__ float lw[16 * 64 * 17];

  const float* src = bv + (size_t)blk * 65536 + (size_t)mt * 16384;
  for (int p = 0; p < 16; ++p) {
    int idx = p * 1024 + tid * 4;
    const float4 v = *(const float4*)(src + idx);
    int o = idx >> 10;
    int i = (idx >> 4) & 63;
    int k = idx & 15;
    float* d = &lw[(o * 64 + i) * 17 + k];
    d[0] = v.x; d[1] = v.y; d[2] = v.z; d[3] = v.w;
  }
  __syncthreads();

  const int e0 = tid * 2;
  const int l  = e0 >> 3;
  const int j  = e0 & 7;
  const int o  = l & 15;
  for (int ks = 0; ks < 32; ++ks) {
    const int k  = ks >> 1;
    const int i0 = (ks & 1) * 32 + (l >> 4) * 8 + j;
    const float a = lw[(o * 64 + i0) * 17 + k];
    const float b = lw[(o * 64 + i0 + 1) * 17 + k];
    const uint16_t ba = __builtin_bit_cast(uint16_t, (bf16_t)a);
    const uint16_t bb = __builtin_bit_cast(uint16_t, (bf16_t)b);
    const uint32_t packed = (uint32_t)ba | ((uint32_t)bb << 16);
    const size_t off = ((((size_t)blk * 32 + ks) * 4 + mt) * 512) + e0;
    *(uint32_t*)(wpk + off) = packed;
  }
}

// ---------------------------------------------------------------------------
// Zero the halo rows of S.
// ---------------------------------------------------------------------------
__global__ __launch_bounds__(256) void padzero_kernel(bf16_t* __restrict__ S)
{
  const int p = blockIdx.x;  // 0..79
  const size_t g = (p < 64) ? ((size_t)(p >> 4) * SROWS + (p & 15))
                            : ((size_t)4 * SROWS + (p - 64));
  uint4 z = {0u, 0u, 0u, 0u};
  *(uint4*)(S + g * C_LEN + (size_t)threadIdx.x * 8) = z;
}

// ---------------------------------------------------------------------------
// x prepass: f32 [n][c][t] -> bf16 S[n][16+t][c'], c' = c ^ ((t&7)<<3)
// within each 64-ch block (XOR swizzle baked into global layout).
// ---------------------------------------------------------------------------
__global__ __launch_bounds__(256) void xprep_kernel(
    const float* __restrict__ x, bf16_t* __restrict__ S)
{
  const int tb = blockIdx.x, cb = blockIdx.y, n = blockIdx.z;
  const int tid = threadIdx.x;
  __shared__ float lt[64 * 67 + 4];

  #pragma unroll
  for (int p = 0; p < 4; ++p) {
    const int idx = p * 256 + tid;
    const int c   = idx >> 4;
    const int t4  = (idx & 15) * 4;
    const float4 v = *(const float4*)(
        x + ((size_t)n * C_LEN + cb * 64 + c) * T_LEN + tb * 64 + t4);
    float* d = &lt[c * 67 + t4];
    d[0] = v.x; d[1] = v.y; d[2] = v.z; d[3] = v.w;
  }
  __syncthreads();

  #pragma unroll
  for (int p = 0; p < 2; ++p) {
    const int idx = p * 256 + tid;
    const int tl  = idx >> 3;
    const int seg = idx & 7;
    const int t   = tb * 64 + tl;
    const int cbase = (seg * 8) ^ ((t & 7) << 3);
    uint32_t w[4];
    #pragma unroll
    for (int h = 0; h < 4; ++h) {
      const float a = lt[(cbase + 2 * h) * 67 + tl];
      const float b = lt[(cbase + 2 * h + 1) * 67 + tl];
      const uint16_t ba = __builtin_bit_cast(uint16_t, (bf16_t)a);
      const uint16_t bb = __builtin_bit_cast(uint16_t, (bf16_t)b);
      w[h] = (uint32_t)ba | ((uint32_t)bb << 16);
    }
    uint4 u4 = {w[0], w[1], w[2], w[3]};
    *(uint4*)(S + ((size_t)n * SROWS + 16 + t) * C_LEN + cb * 64 + seg * 8) = u4;
  }
}

// ---------------------------------------------------------------------------
// Main kernel: 256 thr (4 waves), ~76.5 KB LDS -> 2 WG/CU (8 waves/CU).
// Wave wv: output rows [tr*64,+64) x t-cols [t0+wv*64,+64) (64x64 tile).
// m201-style phase pipeline: 16 phases/block of 2 ks; fragment ds_reads
// issue PRE-barrier (end of phase c) and are consumed after lgkmcnt(0) in
// phase c+1 -> LDS pipe overlaps the MFMA stretch.
// W: ring-5 x 8KB slots, GLL issue distance 4 chunks (2 GLL/thread/chunk).
// Barrier-safety: GLL into slot (c+4)%5 overwrites chunk c-1, whose frag
// reads were lgkm-drained at phase c-1 entry -- one full barrier earlier.
// Cross-wave landing: reads at end of phase q need all-waves W(q+1) landed
// at barrier(q-1) <= each wave's end-of-(q-1) vmcnt(4) covers W(q+1)
// (outstanding there = [W(q+1):2, W(q+2):2, W(q+3):2] -> drain to 4).
// Ledger (per-wave GLL counts; x only at seam, drained by seam wait):
//  seam: issue x:9, W0..W3:8 -> vmcnt(4) (x,W0,W1 landed; W2,W3 fly);
//  phase c<=11: issue W(c+4):2, end vmcnt(4); c=12: vmcnt(2);
//  c=13,14: vmcnt(0); c=15: no tail reads.
// ---------------------------------------------------------------------------
__global__ __launch_bounds__(256, 2) void bsconv_kernel(
    const bf16_t* __restrict__ S, const bf16_t* __restrict__ wpk,
    const int* __restrict__ cols, const int* __restrict__ rows,
    float* __restrict__ y)
{
  const int tt = blockIdx.x, tr = blockIdx.y, n = blockIdx.z;
  const int t0 = tt * TN;
  const int tid = threadIdx.x;
  const int lane = tid & 63, wv = tid >> 6;   // wv 0..3

  __shared__ __attribute__((aligned(16))) bf16_t xst[XROWS * 64];   // 36864 B
  __shared__ __attribute__((aligned(16))) bf16_t wring[5][4096];    // 40960 B
  __shared__ int alist[NB];                   // packed: blk | (col<<8)
  __shared__ unsigned long long wmask[2];

  // ---- build active-block list (order-preserving => deterministic) ----
  {
    const int r  = (tid < NB) ? rows[tid] : -1;
    const int cb = (tid < NB) ? cols[tid] : 0;
    const bool match = (r == tr);
    const unsigned long long m = __ballot(match);
    if (wv < 2 && lane == 0) wmask[wv] = m;
    __syncthreads();
    if (match) {
      int pos = __popcll(wmask[wv] & ((1ull << lane) - 1ull));
      if (wv == 1) pos += __popcll(wmask[0]);
      alist[pos] = tid | (cb << 8);
    }
    __syncthreads();   // also drains all vmem: ledger starts at 0
  }
  const int cnt = __popcll(wmask[0]) + __popcll(wmask[1]);

  f32x4 acc[4][4];
  #pragma unroll
  for (int a = 0; a < 4; ++a)
    #pragma unroll
    for (int b = 0; b < 4; ++b) {
      f32x4 z = {0.f, 0.f, 0.f, 0.f};
      acc[a][b] = z;
    }

  const size_t srow0 = (size_t)n * SROWS + t0;  // S row of LDS row u=0
  const int lxb = tid * 16;                     // lane byte within a 4KB round

  auto issue_x = [&](int cb) {                  // 9 rounds = 36 KB, single buf
    #pragma unroll
    for (int q = 0; q < 9; ++q) {
      const int lb = q * 4096 + lxb;
      const int u  = lb >> 7;                   // LDS row (128 B rows)
      const int ib = (lb >> 1) & 63;
      GLL(S + (srow0 + u) * C_LEN + cb * 64 + ib, (char*)xst + lb);
    }
  };
  auto issue_wc = [&](const bf16_t* wblk, int c, int slot) {  // 8KB chunk
    const bf16_t* wsrc = wblk + (size_t)c * 4096;
    #pragma unroll
    for (int p = 0; p < 2; ++p) {
      const int lb = p * 4096 + lxb;
      GLL(wsrc + (lb >> 1), (char*)wring[slot] + lb);
    }
  };

  // fragment registers: phase c covers ks = 2c+kk (k = c, ih = kk*32)
  bf16x8 afr[2][4], bfr[2][4];
  auto read_frags = [&](int c) {
    const bf16_t* wl = wring[c % 5];
    #pragma unroll
    for (int kk = 0; kk < 2; ++kk) {
      #pragma unroll
      for (int mt = 0; mt < 4; ++mt)
        afr[kk][mt] = *(const bf16x8*)(wl + ((kk * 4 + mt) * 64 + lane) * 8);
      const int ub   = wv * 64 + (lane & 15) + c + 1;
      const int scol = (kk * 32 + ((lane >> 4) & 3) * 8) ^ ((ub & 7) << 3);
      #pragma unroll
      for (int nt = 0; nt < 4; ++nt)
        bfr[kk][nt] = *(const bf16x8*)(xst + (ub + nt * 16) * 64 + scol);
    }
  };

  for (int j = 0; j < cnt; ++j) {
    const int aj = alist[j];
    const bf16_t* wblk = wpk + (size_t)(aj & 255) * 65536;
    const int cb = aj >> 8;

    // ---- seam: stage x (safe: all prior xst reads lgkm-drained a barrier
    // ago) + W prologue chunks 0..3 into slots 0..3 ----
    issue_x(cb);
    issue_wc(wblk, 0, 0);
    issue_wc(wblk, 1, 1);
    issue_wc(wblk, 2, 2);
    issue_wc(wblk, 3, 3);
    asm volatile("s_waitcnt vmcnt(4)" ::: "memory");  // x,W0,W1 landed
    __builtin_amdgcn_s_barrier();
    read_frags(0);                                    // post-barrier (seam cost)

    for (int c = 0; c < 16; ++c) {
      asm volatile("s_waitcnt lgkmcnt(0)" ::: "memory");  // frags(c) ready
      __builtin_amdgcn_sched_barrier(0);                  // rule 18
      if (c <= 11) issue_wc(wblk, c + 4, (c + 4) % 5);
      __builtin_amdgcn_s_setprio(1);
      #pragma unroll
      for (int kk = 0; kk < 2; ++kk)
        #pragma unroll
        for (int mt = 0; mt < 4; ++mt)
          #pragma unroll
          for (int nt = 0; nt < 4; ++nt)
            acc[mt][nt] = __builtin_amdgcn_mfma_f32_16x16x32_bf16(
                afr[kk][mt], bfr[kk][nt], acc[mt][nt], 0, 0, 0);
      __builtin_amdgcn_s_setprio(0);
      __builtin_amdgcn_sched_barrier(0);
      if (c < 15) {
        // counted wait, then PRE-barrier reads of frags(c+1)
        if (c <= 11)      asm volatile("s_waitcnt vmcnt(4)" ::: "memory");
        else if (c == 12) asm volatile("s_waitcnt vmcnt(2)" ::: "memory");
        else              asm volatile("s_waitcnt vmcnt(0)" ::: "memory");
        read_frags(c + 1);
        __builtin_amdgcn_sched_barrier(0);   // pin reads before the barrier
      }
      __builtin_amdgcn_s_barrier();
    }
  }

  // ---- store (each output element exactly once; empty rows store zeros) ----
  const int mlo = ((lane >> 4) & 3) * 4, nn = lane & 15;
  #pragma unroll
  for (int mt = 0; mt < 4; ++mt) {
    #pragma unroll
    for (int nt = 0; nt < 4; ++nt) {
      const int t = t0 + wv * 64 + nt * 16 + nn;
      float* yp = y + ((size_t)n * C_LEN + (size_t)(tr * 64 + mt * 16 + mlo)) * T_LEN + t;
      #pragma unroll
      for (int r = 0; r < 4; ++r)
        yp[(size_t)r * T_LEN] = acc[mt][nt][r];
    }
  }
}

extern "C" void kernel_launch(void* const* d_in, const int* in_sizes, int n_in,
                              void* d_out, int out_size, void* d_ws, size_t ws_size,
                              hipStream_t stream) {
  const float* x   = (const float*)d_in[0];
  const float* bv  = (const float*)d_in[1];
  const int* cols  = (const int*)d_in[2];
  const int* rows  = (const int*)d_in[3];
  float* y = (float*)d_out;

  // ws layout: [wpk: 16,777,216 B][S: 33,882,112 B]  (needs ws >= 50.7 MB)
  bf16_t* wpk = (bf16_t*)d_ws;
  bf16_t* S   = (bf16_t*)((char*)d_ws + 16777216);

  prepack_kernel<<<dim3(128, 4), dim3(256), 0, stream>>>(bv, wpk);
  padzero_kernel<<<dim3(80), dim3(256), 0, stream>>>(S);
  xprep_kernel<<<dim3(32, 32, 4), dim3(256), 0, stream>>>(x, S);
  bsconv_kernel<<<dim3(8, 32, 4), dim3(256), 0, stream>>>(S, wpk, cols, rows, y);
}